// Round 5
// baseline (246.191 us; speedup 1.0000x reference)
//
#include <hip/hip_runtime.h>

#define N 4096
#define NB 32      // N / 128
#define CH 8       // split-K chunk = CH 128-blocks (<=32 BK32 stages per unit)

typedef __bf16 bf16;
typedef bf16 bf16x4 __attribute__((ext_vector_type(4)));
typedef bf16 bf16x8 __attribute__((ext_vector_type(8)));
typedef float f32x4 __attribute__((ext_vector_type(4)));

__device__ __forceinline__ int tri(int i) { return (i * (i + 1)) >> 1; }

// async global(16B) -> LDS, wave-uniform LDS base + lane*16
__device__ __forceinline__ void async16(const bf16* g, const bf16* l) {
    __builtin_amdgcn_global_load_lds(
        (const __attribute__((address_space(1))) unsigned int*)g,
        (__attribute__((address_space(3))) unsigned int*)l, 16, 0, 0);
}

// s_waitcnt imm: vmcnt[3:0], expcnt[6:4]=7 (no wait), lgkmcnt[11:8]=15 (no wait)
#define WAITCNT_VM(n) (0xF70 | (n))

// ---- prepass 1: A (fp32, row-major) -> block-compacted bf16 tiles ----
__global__ __launch_bounds__(256) void conv_a(const float* __restrict__ A,
                                              bf16* __restrict__ Abf) {
    const int bk = blockIdx.x, bi = blockIdx.y;
    if (bk > bi) return;
    bf16* slot = Abf + (size_t)(tri(bi) + bk) * 16384;
    const int tid = threadIdx.x;
#pragma unroll
    for (int it = 0; it < 8; ++it) {
        const int c = it * 256 + tid;
        const int row = c >> 4, col8 = c & 15;
        const float* src = &A[(size_t)(bi * 128 + row) * N + bk * 128 + col8 * 8];
        f32x4 v0 = *(const f32x4*)src;
        f32x4 v1 = *(const f32x4*)(src + 4);
        bf16x8 h = { (bf16)v0[0], (bf16)v0[1], (bf16)v0[2], (bf16)v0[3],
                     (bf16)v1[0], (bf16)v1[1], (bf16)v1[2], (bf16)v1[3] };
        *(bf16x8*)&slot[row * 128 + col8 * 8] = h;
    }
}

// ---- prepass 2: B (fp32) -> block-compacted bf16 TRANSPOSED tiles ----
__global__ __launch_bounds__(256) void conv_bt(const float* __restrict__ B,
                                               bf16* __restrict__ Btf) {
    const int bk = blockIdx.x, bn = blockIdx.y;
    if (bk < bn) return;
    bf16* slot = Btf + (size_t)(tri(bk) + bn) * 16384;
    const int tid = threadIdx.x;
    const int kq = tid >> 5;
    const int n4 = tid & 31;
#pragma unroll
    for (int it = 0; it < 4; ++it) {
        const int kl = it * 32 + kq * 4;
        const float* src = &B[(size_t)(bk * 128 + kl) * N + bn * 128 + n4 * 4];
        f32x4 r0 = *(const f32x4*)(src + 0 * N);
        f32x4 r1 = *(const f32x4*)(src + 1 * N);
        f32x4 r2 = *(const f32x4*)(src + 2 * N);
        f32x4 r3 = *(const f32x4*)(src + 3 * N);
#pragma unroll
        for (int i = 0; i < 4; ++i) {
            bf16x4 h = { (bf16)r0[i], (bf16)r1[i], (bf16)r2[i], (bf16)r3[i] };
            *(bf16x4*)&slot[(n4 * 4 + i) * 128 + kl] = h;
        }
    }
}

// ---- zero C ----
__global__ __launch_bounds__(256) void zero_c(float* __restrict__ C) {
    f32x4* p = (f32x4*)C;
    const int base = blockIdx.x * 1024 + threadIdx.x;
#pragma unroll
    for (int it = 0; it < 4; ++it)
        p[base + it * 256] = (f32x4){0.f, 0.f, 0.f, 0.f};
}

// ---- main: BK32 double-buffered async pipeline, raw s_barrier + vmcnt(4) ----
// LDS chunk (row,kg) at index row*4 + (kg ^ (row&3)) (conflict-free b128 reads;
// inverse swizzle applied to the per-lane global address at staging).
__global__ __launch_bounds__(256) void tril_mm_kernel(const bf16* __restrict__ Abf,
                                                      const bf16* __restrict__ Btf,
                                                      float* __restrict__ C) {
    // ---- decode: bi-major (descending) so same-bi units co-run (A-tile L2 reuse)
    int id = blockIdx.x;
    int bi = NB - 1;
    for (; bi > 0; --bi) {
        const int T = bi + 1, q = T >> 3, r = T & 7;
        const int cnt = 4 * q * (q + 1) + r * (q + 1);   // units with this bi
        if (id < cnt) break;
        id -= cnt;
    }
    int bj = 0;
    for (;;) {
        const int S = ((bi - bj) >> 3) + 1;
        if (id < S) break;
        id -= S; ++bj;
    }
    const int cidx = id;
    const int Ssplit = ((bi - bj) >> 3) + 1;
    const int kb_start = bj + cidx * CH;
    const int kb_end   = min(kb_start + CH, bi + 1);
    const int triBi = tri(bi);

    __shared__ __align__(16) bf16 As[2][128 * 32];   // 8 KB each
    __shared__ __align__(16) bf16 Bs[2][128 * 32];

    const int tid = threadIdx.x;
    const int wave = tid >> 6;
    const int wm = (wave >> 1) * 64;
    const int wn = (wave & 1) * 64;
    const int l15 = tid & 15;
    const int quad = (tid & 63) >> 4;
    const int wbase = tid & ~63;

    int goff[2];
#pragma unroll
    for (int r = 0; r < 2; ++r) {
        const int s = r * 256 + tid;          // LDS chunk this lane fills
        const int row = s >> 2;
        const int kg = (s & 3) ^ (row & 3);   // inverse swizzle
        goff[r] = row * 128 + kg * 8;
    }
    int ach[4], bch[4];
#pragma unroll
    for (int i = 0; i < 4; ++i) {
        const int m = wm + i * 16 + l15;
        const int n = wn + i * 16 + l15;
        ach[i] = m * 4 + (quad ^ (m & 3));
        bch[i] = n * 4 + (quad ^ (n & 3));
    }

    const int nstage = (kb_end - kb_start) << 2;   // BK32 stages

    auto issue = [&](int s, int half) {
        const int kb = kb_start + (s >> 2);
        const int kk = (s & 3) << 5;
        const bf16* Ab = Abf + (size_t)(triBi + kb) * 16384 + kk;
        const bf16* Bb = Btf + (size_t)(tri(kb) + bj) * 16384 + kk;
#pragma unroll
        for (int r = 0; r < 2; ++r) {
            async16(Ab + goff[r], &As[half][(r * 256 + wbase) * 8]);
            async16(Bb + goff[r], &Bs[half][(r * 256 + wbase) * 8]);
        }
    };

    f32x4 acc[4][4] = {};
    issue(0, 0);
    for (int s = 0; s < nstage; ++s) {
        const int cur = s & 1;
        if (s + 1 < nstage) {
            issue(s + 1, cur ^ 1);                         // 4 loads in flight
            __builtin_amdgcn_s_waitcnt(WAITCNT_VM(4));     // wait only stage-s loads
        } else {
            __builtin_amdgcn_s_waitcnt(WAITCNT_VM(0));
        }
        __builtin_amdgcn_s_barrier();                      // stage-s data visible

        bf16x8 af[4], bfr[4];
#pragma unroll
        for (int i = 0; i < 4; ++i) {
            af[i]  = *(const bf16x8*)&As[cur][ach[i] * 8];
            bfr[i] = *(const bf16x8*)&Bs[cur][bch[i] * 8];
        }
#pragma unroll
        for (int i = 0; i < 4; ++i)
#pragma unroll
            for (int j = 0; j < 4; ++j)
                acc[i][j] = __builtin_amdgcn_mfma_f32_16x16x32_bf16(af[i], bfr[j], acc[i][j], 0, 0, 0);

        if (s + 1 < nstage)
            __builtin_amdgcn_s_barrier();   // all reads of buf[cur] done before s+1 overwrites it
    }

    // ---- epilogue: C/D layout col = lane&15, row = quad*4 + v ----
    // Diagonal tiles store unpredicated: exact triangular inputs give exact +0 above diag.
    const int row0 = bi * 128, col0 = bj * 128;
    if (Ssplit == 1) {
#pragma unroll
        for (int i = 0; i < 4; ++i)
#pragma unroll
            for (int j = 0; j < 4; ++j) {
                const int colg = col0 + wn + j * 16 + l15;
#pragma unroll
                for (int v = 0; v < 4; ++v) {
                    const int rowg = row0 + wm + i * 16 + quad * 4 + v;
                    C[(size_t)rowg * N + colg] = acc[i][j][v];
                }
            }
    } else {
#pragma unroll
        for (int i = 0; i < 4; ++i)
#pragma unroll
            for (int j = 0; j < 4; ++j) {
                const int colg = col0 + wn + j * 16 + l15;
#pragma unroll
                for (int v = 0; v < 4; ++v) {
                    const int rowg = row0 + wm + i * 16 + quad * 4 + v;
                    atomicAdd(&C[(size_t)rowg * N + colg], acc[i][j][v]);
                }
            }
    }
}

extern "C" void kernel_launch(void* const* d_in, const int* in_sizes, int n_in,
                              void* d_out, int out_size, void* d_ws, size_t ws_size,
                              hipStream_t stream) {
    const float* A = (const float*)d_in[0];
    const float* B = (const float*)d_in[1];
    float* C = (float*)d_out;
    bf16* Abf = (bf16*)d_ws;                       // 528 tiles x 32 KB = 16.5 MiB
    bf16* Btf = Abf + (size_t)528 * 16384;         // another 16.5 MiB

    conv_a <<<dim3(NB, NB), dim3(256), 0, stream>>>(A, Abf);
    conv_bt<<<dim3(NB, NB), dim3(256), 0, stream>>>(B, Btf);
    zero_c <<<dim3(4096),   dim3(256), 0, stream>>>(C);
    tril_mm_kernel<<<dim3(1000), dim3(256), 0, stream>>>(Abf, Btf, C);
}